// Round 12
// baseline (167.157 us; speedup 1.0000x reference)
//
#include <hip/hip_runtime.h>

#define NPIX (512*512)
#define KCL 16
#define IMG_STRIDE 1088   // per-image floats: [0..15]=cnt, [32..543]=sums[16][32], [544..1055]=sq[16][32]
#define LAB_OFF 8704      // float offset of packed-u8 label region (= 8*IMG_STRIDE)
#define ZERO_BYTES (LAB_OFF * 4)

typedef __attribute__((ext_vector_type(8))) short bf16x8;
typedef __attribute__((ext_vector_type(4))) float f32x4;
typedef __attribute__((ext_vector_type(4))) int i32x4;

// fp32 -> bf16 round-to-nearest-even
static __device__ __forceinline__ unsigned int bf16rne(float x) {
  unsigned int u = __builtin_bit_cast(unsigned int, x);
  u += 0x7FFFu + ((u >> 16) & 1u);
  return u >> 16;
}
static __device__ __forceinline__ int pk2(float a, float b) {
  return (int)(bf16rne(a) | (bf16rne(b) << 16));
}

#define RS_LEVEL(ARR, HALF, MASK) { \
    const bool hi = (lane & (MASK)) != 0; \
    _Pragma("unroll") \
    for (int j = 0; j < (HALF); ++j) { \
      float send = hi ? ARR[j] : ARR[j + (HALF)]; \
      float recv = __shfl_xor(send, (MASK), 64); \
      ARR[j] = (hi ? ARR[j + (HALF)] : ARR[j]) + recv; \
    } }

// ---------------- prep: pack labels to u8 + per-image cnt (R9-proven) ----------------
__global__ void __launch_bounds__(512)
cl_prep(const int* __restrict__ labs, float* __restrict__ ws)
{
  const int b    = blockIdx.x >> 4;
  const int seg  = blockIdx.x & 15;
  const int tid  = threadIdx.x;
  const int lane = tid & 63;
  const int4* lb4 = reinterpret_cast<const int4*>(labs + b * NPIX + seg * 16384);
  unsigned int* lab8 = reinterpret_cast<unsigned int*>(ws + LAB_OFF) +
                       (b * NPIX + seg * 16384) / 4;

  float c[KCL];
  #pragma unroll
  for (int k = 0; k < KCL; ++k) c[k] = 0.f;
  #pragma unroll
  for (int i = 0; i < 8; ++i) {
    const int4 v = lb4[tid + i * 512];
    lab8[tid + i * 512] = (unsigned int)(v.x & 15) | ((unsigned int)(v.y & 15) << 8) |
                          ((unsigned int)(v.z & 15) << 16) | ((unsigned int)(v.w & 15) << 24);
    #pragma unroll
    for (int k = 0; k < KCL; ++k) {
      c[k] += (v.x == k) ? 1.0f : 0.0f;
      c[k] += (v.y == k) ? 1.0f : 0.0f;
      c[k] += (v.z == k) ? 1.0f : 0.0f;
      c[k] += (v.w == k) ? 1.0f : 0.0f;
    }
  }
  RS_LEVEL(c, 8, 1)
  RS_LEVEL(c, 4, 2)
  RS_LEVEL(c, 2, 4)
  RS_LEVEL(c, 1, 8)
  c[0] += __shfl_xor(c[0], 16, 64);
  c[0] += __shfl_xor(c[0], 32, 64);
  if (lane < KCL) {
    const int v4 = (int)(__brev((unsigned)lane) >> 28);
    atomicAdd(&ws[b * IMG_STRIDE + v4], c[0]);
  }
}

// ---------------- accum: linear-stream one-hot MFMA, counted-vmcnt pipeline ----------------
// grid 512 = 8 img x 4 chgroups(8ch) x 16 pxtiles(16384 px); 512 thr = 8 waves.
// Wave w streams channel cg*8+w linearly (64 KB contiguous; 4 KB/round x 16 rounds).
// Single LDS buffer; per round: COMPUTE(r) -> bar -> load r+2 to regs,
// ds_write r+1 (compiler emits COUNTED vmcnt(4), r+2 stays in flight) -> bar.
// Raw s_barrier + lgkmcnt(0) only: no vmcnt(0) drain anywhere in the loop.
__global__ void __launch_bounds__(512)
cl_accum(const float* __restrict__ feats, float* __restrict__ ws)
{
  const int bid  = blockIdx.x;
  const int pt   = bid & 15;
  const int cg   = (bid >> 4) & 3;
  const int b    = bid >> 6;
  const int tid  = threadIdx.x;
  const int wave = tid >> 6;
  const int lane = tid & 63;
  const int kid  = lane & 15;
  const int sub  = lane >> 4;
  const int px0  = pt * 16384;

  __shared__ float sfeat[8 * 1028];   // channel rows, stride 1028 (16B-aligned)
  __shared__ float red[256];
  if (tid < 256) red[tid] = 0.f;

  const float* fptr = feats + ((long long)(b * 32 + cg * 8 + wave)) * NPIX + px0;
  const unsigned long long* lab64 = reinterpret_cast<const unsigned long long*>(
      reinterpret_cast<const unsigned char*>(ws) + (size_t)ZERO_BYTES + (size_t)b * NPIX + px0);

  f32x4 accs = {0.f, 0.f, 0.f, 0.f};
  f32x4 accq = {0.f, 0.f, 0.f, 0.f};

  float4 pA[4], pB[4];

#define LOADB(P, R) { _Pragma("unroll") for (int i = 0; i < 4; ++i) \
    P[i] = *reinterpret_cast<const float4*>(fptr + (R) * 1024 + i * 256 + lane * 4); }
#define WRITEB(P) { _Pragma("unroll") for (int i = 0; i < 4; ++i) \
    *reinterpret_cast<float4*>(&sfeat[wave * 1028 + i * 256 + lane * 4]) = P[i]; }
#define FENCE() { asm volatile("s_waitcnt lgkmcnt(0)" ::: "memory"); \
    __builtin_amdgcn_s_barrier(); asm volatile("" ::: "memory"); }

#define COMPUTE(R) { \
    unsigned long long lw[4]; \
    _Pragma("unroll") for (int g2 = 0; g2 < 4; ++g2) \
      lw[g2] = lab64[(R) * 128 + wave * 16 + g2 * 4 + sub]; \
    _Pragma("unroll") for (int g2 = 0; g2 < 4; ++g2) { \
      bf16x8 af; \
      _Pragma("unroll") for (int j = 0; j < 8; ++j) \
        af[j] = (short)((((int)(lw[g2] >> (8 * j)) & 0xFF) == kid) ? 0x3F80 : 0); \
      i32x4 wv = {0, 0, 0, 0}, qv = {0, 0, 0, 0}; \
      if (kid < 8) { \
        const float* rp = &sfeat[kid * 1028 + wave * 128 + g2 * 32 + sub * 8]; \
        const float4 x0 = *reinterpret_cast<const float4*>(rp); \
        const float4 x1 = *reinterpret_cast<const float4*>(rp + 4); \
        wv[0] = pk2(x0.x, x0.y); wv[1] = pk2(x0.z, x0.w); \
        wv[2] = pk2(x1.x, x1.y); wv[3] = pk2(x1.z, x1.w); \
        qv[0] = pk2(x0.x * x0.x, x0.y * x0.y); qv[1] = pk2(x0.z * x0.z, x0.w * x0.w); \
        qv[2] = pk2(x1.x * x1.x, x1.y * x1.y); qv[3] = pk2(x1.z * x1.z, x1.w * x1.w); \
      } \
      accs = __builtin_amdgcn_mfma_f32_16x16x32_bf16( \
                 af, __builtin_bit_cast(bf16x8, wv), accs, 0, 0, 0); \
      accq = __builtin_amdgcn_mfma_f32_16x16x32_bf16( \
                 af, __builtin_bit_cast(bf16x8, qv), accq, 0, 0, 0); \
    } }

  // prologue: round 0 -> LDS; round 1 -> pB (in flight)
  LOADB(pA, 0);
  WRITEB(pA);          // compiler waits vmcnt on pA only
  LOADB(pB, 1);
  FENCE();             // round 0 visible to all waves; pB stays in flight

  for (int it = 0; it < 8; ++it) {      // rounds 2it, 2it+1
    COMPUTE(2 * it);
    FENCE();                             // everyone done reading round 2it
    if (2 * it + 2 < 16) LOADB(pA, 2 * it + 2);
    WRITEB(pB);                          // round 2it+1 -> LDS (counted vmcnt)
    FENCE();                             // round 2it+1 visible
    COMPUTE(2 * it + 1);
    FENCE();                             // everyone done reading round 2it+1
    if (2 * it + 3 < 16) LOADB(pB, 2 * it + 3);
    if (2 * it + 2 < 16) { WRITEB(pA); } // round 2it+2 -> LDS
    FENCE();                             // round 2it+2 visible
  }

  // ---- epilogue: D col=kid (channel, <8 valid), row=sub*4+rr (cluster k) ----
  if (kid < 8) {
    #pragma unroll
    for (int rr = 0; rr < 4; ++rr) {
      const int k = sub * 4 + rr;
      atomicAdd(&red[k * 8 + kid],       accs[rr]);
      atomicAdd(&red[128 + k * 8 + kid], accq[rr]);
    }
  }
  __syncthreads();
  if (tid < 128) {
    const int k  = tid >> 3;
    const int ch = (tid & 7) + cg * 8;
    atomicAdd(&ws[b * IMG_STRIDE + 32  + k * 32 + ch], red[tid]);
    atomicAdd(&ws[b * IMG_STRIDE + 544 + k * 32 + ch], red[128 + tid]);
  }
#undef LOADB
#undef WRITEB
#undef FENCE
#undef COMPUTE
}

// ---------------- finalize: 1 block, 512 threads; wave w = image w (R9-proven) ----------------
__global__ void __launch_bounds__(512)
cl_finalize(const float* __restrict__ ws, float* __restrict__ out)
{
  __shared__ float smean[8][KCL][33];
  __shared__ float slossb[8];
  const int tid  = threadIdx.x;
  const int w    = tid >> 6;
  const int lane = tid & 63;
  const float* base = ws + w * IMG_STRIDE;

  const int kl = lane >> 2;
  const float ik = 1.0f / base[kl];

  float m2part = 0.f, sqpart = 0.f;
  #pragma unroll
  for (int j = 0; j < 8; ++j) {
    const int idx = lane * 8 + j;
    const int c = idx & 31;
    const float m = base[32 + idx] * ik;
    smean[w][kl][c] = m;
    m2part = fmaf(m, m, m2part);
    sqpart += base[544 + idx];
  }
  float varp = fmaf(sqpart, ik, -m2part);
  #pragma unroll
  for (int mk = 1; mk < 64; mk <<= 1) varp += __shfl_xor(varp, mk, 64);

  __syncthreads();

  const int kk = lane >> 2, q = lane & 3;
  float n2 = 0.f;
  #pragma unroll
  for (int j = 0; j < 8; ++j) {
    const float m = smean[w][kk][q * 8 + j];
    n2 = fmaf(m, m, n2);
  }
  n2 += __shfl_xor(n2, 1, 64);
  n2 += __shfl_xor(n2, 2, 64);
  float regp = (q == 0) ? sqrtf(n2) : 0.f;
  #pragma unroll
  for (int mk = 1; mk < 64; mk <<= 1) regp += __shfl_xor(regp, mk, 64);

  float hing = 0.f;
  for (int p = lane; p < 120; p += 64) {
    int i = 0, rem = p;
    while (rem >= 15 - i) { rem -= 15 - i; ++i; }
    const int jj = i + 1 + rem;
    float d2 = 0.f;
    #pragma unroll
    for (int c = 0; c < 32; ++c) {
      const float d = smean[w][i][c] - smean[w][jj][c];
      d2 = fmaf(d, d, d2);
    }
    const float h = fmaxf(5.0f - sqrtf(d2), 0.f);   // 2*DD = 5.0
    hing = fmaf(h, h, hing);
  }
  #pragma unroll
  for (int mk = 1; mk < 64; mk <<= 1) hing += __shfl_xor(hing, mk, 64);

  if (lane == 0)
    slossb[w] = (varp + hing * (1.0f / 15.0f) + 0.005f * regp) * (1.0f / 16.0f);
  __syncthreads();
  if (tid == 0) {
    float t = 0.f;
    #pragma unroll
    for (int i = 0; i < 8; ++i) t += slossb[i];
    out[0] = t * (1.0f / 9.0f);
  }
}

extern "C" void kernel_launch(void* const* d_in, const int* in_sizes, int n_in,
                              void* d_out, int out_size, void* d_ws, size_t ws_size,
                              hipStream_t stream)
{
  const float* feats = (const float*)d_in[0];
  const int*   labs  = (const int*)d_in[1];
  float* out = (float*)d_out;
  float* ws  = (float*)d_ws;

  (void)hipMemsetAsync(d_ws, 0, ZERO_BYTES, stream);
  hipLaunchKernelGGL(cl_prep,     dim3(128), dim3(512), 0, stream, labs, ws);
  hipLaunchKernelGGL(cl_accum,    dim3(512), dim3(512), 0, stream, feats, ws);
  hipLaunchKernelGGL(cl_finalize, dim3(1),   dim3(512), 0, stream, ws, out);
}

// Round 13
// 68.847 us; speedup vs baseline: 2.4279x; 2.4279x over previous
//
#include <hip/hip_runtime.h>

#define NPIX (512*512)
#define KCL 16
#define IMG_STRIDE 1088   // per-image floats: [0..15]=cnt, [32..543]=sums[16][32], [544..1055]=sq[16][32]
#define ZERO_BYTES (8 * IMG_STRIDE * 4)

typedef __attribute__((ext_vector_type(8))) short bf16x8;
typedef __attribute__((ext_vector_type(4))) float f32x4;
typedef __attribute__((ext_vector_type(4))) int i32x4;

// fp32 -> bf16 round-to-nearest-even
static __device__ __forceinline__ unsigned int bf16rne(float x) {
  unsigned int u = __builtin_bit_cast(unsigned int, x);
  u += 0x7FFFu + ((u >> 16) & 1u);
  return u >> 16;
}
// pack two fp32 -> one dword of 2 bf16 (RNE), lo = a, hi = b
static __device__ __forceinline__ int pk2(float a, float b) {
  return (int)(bf16rne(a) | (bf16rne(b) << 16));
}

// reduce-scatter one level: keep lo/hi half by lane bit, exchange the other.
#define RS_LEVEL(ARR, HALF, MASK) { \
    const bool hi = (lane & (MASK)) != 0; \
    _Pragma("unroll") \
    for (int j = 0; j < (HALF); ++j) { \
      float send = hi ? ARR[j] : ARR[j + (HALF)]; \
      float recv = __shfl_xor(send, (MASK), 64); \
      ARR[j] = (hi ? ARR[j + (HALF)] : ARR[j]) + recv; \
    } }

// ---------------- accum: one-hot MFMA kernel (R8, proven 68.7 us) ----------------
// 512 blocks = 8 img x 64 pxtiles(4096 px); 512 threads = 8 waves.
// Wave w owns px [w*512, w*512+512) of the tile as 16 groups of 32 px.
// Per group: A = onehot[k=lane&15][px], B = f[px][c] (bf16), two ch-halves,
// MFMA for sums and for squares. D col=lane&15 (channel-within-half),
// row=(lane>>4)*4+r (cluster k). A and B share the same k-slot->px map
// (any bijection is valid since the result sums over px).
__global__ void __launch_bounds__(512)
cl_accum(const float* __restrict__ feats, const int* __restrict__ labs,
         float* __restrict__ ws)
{
  const int bid  = blockIdx.x;
  const int tile = bid & 63;
  const int b    = bid >> 6;
  const int tid  = threadIdx.x;
  const int wave = tid >> 6;
  const int lane = tid & 63;
  const int px0  = tile * 4096;

  __shared__ unsigned int slabw[1024];   // packed u8 labels, 4096 px
  __shared__ float red[1024];            // [0..511]=sums[16][32], [512..1023]=sq
  __shared__ float hpart[8][KCL];

  // ---- stage labels (packed u8) + per-thread histogram of its 8 labels ----
  {
    float c[KCL];
    #pragma unroll
    for (int k = 0; k < KCL; ++k) c[k] = 0.f;
    const int4* lb4 = reinterpret_cast<const int4*>(labs + b * NPIX + px0);
    #pragma unroll
    for (int i = 0; i < 2; ++i) {
      const int4 v = lb4[tid + i * 512];
      slabw[tid + i * 512] = (unsigned int)v.x | ((unsigned int)v.y << 8) |
                             ((unsigned int)v.z << 16) | ((unsigned int)v.w << 24);
      #pragma unroll
      for (int k = 0; k < KCL; ++k) {
        c[k] += (v.x == k) ? 1.0f : 0.0f;
        c[k] += (v.y == k) ? 1.0f : 0.0f;
        c[k] += (v.z == k) ? 1.0f : 0.0f;
        c[k] += (v.w == k) ? 1.0f : 0.0f;
      }
    }
    red[tid] = 0.f;
    red[tid + 512] = 0.f;
    RS_LEVEL(c, 8, 1)
    RS_LEVEL(c, 4, 2)
    RS_LEVEL(c, 2, 4)
    RS_LEVEL(c, 1, 8)
    c[0] += __shfl_xor(c[0], 16, 64);
    c[0] += __shfl_xor(c[0], 32, 64);
    if (lane < KCL) {
      const int v4 = (int)(__brev((unsigned)lane) >> 28);
      hpart[wave][v4] = c[0];
    }
  }
  __syncthreads();
  if (tid < KCL) {
    float t = 0.f;
    #pragma unroll
    for (int w = 0; w < 8; ++w) t += hpart[w][tid];
    atomicAdd(&ws[b * IMG_STRIDE + tid], t);   // cnt
  }

  // ---- main MFMA loop ----
  const int kid = lane & 15;
  const int sub = lane >> 4;             // 0..3
  const float* fA = feats + ((long long)(b * 32 + kid)) * NPIX
                    + px0 + wave * 512 + sub * 8;
  const float* fB = fA + (long long)16 * NPIX;
  const unsigned long long* slq =
      reinterpret_cast<const unsigned long long*>(slabw) + wave * 64 + sub;

  f32x4 accs0 = {0.f, 0.f, 0.f, 0.f};
  f32x4 accs1 = {0.f, 0.f, 0.f, 0.f};
  f32x4 accq0 = {0.f, 0.f, 0.f, 0.f};
  f32x4 accq1 = {0.f, 0.f, 0.f, 0.f};

  #pragma unroll 4
  for (int g = 0; g < 16; ++g) {
    const unsigned long long lw = slq[g * 4];   // 8 labels for this lane's px
    bf16x8 af;
    #pragma unroll
    for (int j = 0; j < 8; ++j)
      af[j] = (short)((((int)(lw >> (8 * j)) & 0xFF) == kid) ? 0x3F80 : 0);

    // half 0: channels [0..15]
    {
      const float4 x0 = *reinterpret_cast<const float4*>(fA + g * 32);
      const float4 x1 = *reinterpret_cast<const float4*>(fA + g * 32 + 4);
      i32x4 wv, qv;
      wv[0] = pk2(x0.x, x0.y); wv[1] = pk2(x0.z, x0.w);
      wv[2] = pk2(x1.x, x1.y); wv[3] = pk2(x1.z, x1.w);
      qv[0] = pk2(x0.x * x0.x, x0.y * x0.y); qv[1] = pk2(x0.z * x0.z, x0.w * x0.w);
      qv[2] = pk2(x1.x * x1.x, x1.y * x1.y); qv[3] = pk2(x1.z * x1.z, x1.w * x1.w);
      accs0 = __builtin_amdgcn_mfma_f32_16x16x32_bf16(
                  af, __builtin_bit_cast(bf16x8, wv), accs0, 0, 0, 0);
      accq0 = __builtin_amdgcn_mfma_f32_16x16x32_bf16(
                  af, __builtin_bit_cast(bf16x8, qv), accq0, 0, 0, 0);
    }
    // half 1: channels [16..31]
    {
      const float4 x0 = *reinterpret_cast<const float4*>(fB + g * 32);
      const float4 x1 = *reinterpret_cast<const float4*>(fB + g * 32 + 4);
      i32x4 wv, qv;
      wv[0] = pk2(x0.x, x0.y); wv[1] = pk2(x0.z, x0.w);
      wv[2] = pk2(x1.x, x1.y); wv[3] = pk2(x1.z, x1.w);
      qv[0] = pk2(x0.x * x0.x, x0.y * x0.y); qv[1] = pk2(x0.z * x0.z, x0.w * x0.w);
      qv[2] = pk2(x1.x * x1.x, x1.y * x1.y); qv[3] = pk2(x1.z * x1.z, x1.w * x1.w);
      accs1 = __builtin_amdgcn_mfma_f32_16x16x32_bf16(
                  af, __builtin_bit_cast(bf16x8, wv), accs1, 0, 0, 0);
      accq1 = __builtin_amdgcn_mfma_f32_16x16x32_bf16(
                  af, __builtin_bit_cast(bf16x8, qv), accq1, 0, 0, 0);
    }
  }

  // ---- cross-wave LDS reduce, then per-block global atomics ----
  #pragma unroll
  for (int r = 0; r < 4; ++r) {
    const int k = sub * 4 + r;
    atomicAdd(&red[k * 32 + kid],            accs0[r]);
    atomicAdd(&red[k * 32 + 16 + kid],       accs1[r]);
    atomicAdd(&red[512 + k * 32 + kid],      accq0[r]);
    atomicAdd(&red[512 + k * 32 + 16 + kid], accq1[r]);
  }
  __syncthreads();
  atomicAdd(&ws[b * IMG_STRIDE + 32 + tid],  red[tid]);        // sums
  atomicAdd(&ws[b * IMG_STRIDE + 544 + tid], red[512 + tid]);  // sq
}

// ---------------- finalize: 1 block, 512 threads; wave w = image w ----------------
__global__ void __launch_bounds__(512)
cl_finalize(const float* __restrict__ ws, float* __restrict__ out)
{
  __shared__ float smean[8][KCL][33];
  __shared__ float slossb[8];
  const int tid  = threadIdx.x;
  const int w    = tid >> 6;
  const int lane = tid & 63;
  const float* base = ws + w * IMG_STRIDE;

  // lane covers 8 entries idx=lane*8+j, all with k = lane>>2
  const int kl = lane >> 2;
  const float ik = 1.0f / base[kl];

  float m2part = 0.f, sqpart = 0.f;
  #pragma unroll
  for (int j = 0; j < 8; ++j) {
    const int idx = lane * 8 + j;
    const int c = idx & 31;
    const float m = base[32 + idx] * ik;
    smean[w][kl][c] = m;
    m2part = fmaf(m, m, m2part);
    sqpart += base[544 + idx];
  }
  float varp = fmaf(sqpart, ik, -m2part);
  #pragma unroll
  for (int mk = 1; mk < 64; mk <<= 1) varp += __shfl_xor(varp, mk, 64);
  // varp == var_loss on all lanes

  __syncthreads();

  // reg term: 4 lanes per cluster k
  const int kk = lane >> 2, q = lane & 3;
  float n2 = 0.f;
  #pragma unroll
  for (int j = 0; j < 8; ++j) {
    const float m = smean[w][kk][q * 8 + j];
    n2 = fmaf(m, m, n2);
  }
  n2 += __shfl_xor(n2, 1, 64);
  n2 += __shfl_xor(n2, 2, 64);
  float regp = (q == 0) ? sqrtf(n2) : 0.f;
  #pragma unroll
  for (int mk = 1; mk < 64; mk <<= 1) regp += __shfl_xor(regp, mk, 64);

  // pairwise hinge over 120 pairs
  float hing = 0.f;
  for (int p = lane; p < 120; p += 64) {
    int i = 0, rem = p;
    while (rem >= 15 - i) { rem -= 15 - i; ++i; }
    const int jj = i + 1 + rem;
    float d2 = 0.f;
    #pragma unroll
    for (int c = 0; c < 32; ++c) {
      const float d = smean[w][i][c] - smean[w][jj][c];
      d2 = fmaf(d, d, d2);
    }
    const float h = fmaxf(5.0f - sqrtf(d2), 0.f);   // 2*DD = 5.0
    hing = fmaf(h, h, hing);
  }
  #pragma unroll
  for (int mk = 1; mk < 64; mk <<= 1) hing += __shfl_xor(hing, mk, 64);

  if (lane == 0)
    slossb[w] = (varp + hing * (1.0f / 15.0f) + 0.005f * regp) * (1.0f / 16.0f);
  __syncthreads();
  if (tid == 0) {
    float t = 0.f;
    #pragma unroll
    for (int i = 0; i < 8; ++i) t += slossb[i];
    out[0] = t * (1.0f / 9.0f);
  }
}

extern "C" void kernel_launch(void* const* d_in, const int* in_sizes, int n_in,
                              void* d_out, int out_size, void* d_ws, size_t ws_size,
                              hipStream_t stream)
{
  const float* feats = (const float*)d_in[0];
  const int*   labs  = (const int*)d_in[1];
  float* out = (float*)d_out;
  float* ws  = (float*)d_ws;

  (void)hipMemsetAsync(d_ws, 0, ZERO_BYTES, stream);
  hipLaunchKernelGGL(cl_accum,    dim3(512), dim3(512), 0, stream, feats, labs, ws);
  hipLaunchKernelGGL(cl_finalize, dim3(1),   dim3(512), 0, stream, ws, out);
}